// Round 6
// baseline (952.359 us; speedup 1.0000x reference)
//
#include <hip/hip_runtime.h>

// ---------------------------------------------------------------------------
// MultiEdgeClassifier: 6-layer GCN + BN + weighted residual + edge-pair FC
// N=100k nodes, HID=128, E=1.6M edges (+N self loops), E_OUT=400k
// Round 5: factored norm (dis[s] into GEMM epilogue, dis[d] at flush),
//          4B edge records (src<<6), scalarized segmented SpMM (saddr
//          gathers, SALU bookkeeping), 16-deep gather pipeline.
// ---------------------------------------------------------------------------

#define NW 8192      // waves for spmm (2048 blocks x 4)
#define BKT 128      // dsts per bucket
#define CAP 6144     // max edges per bucket staged in LDS (mean ~2175)

typedef __attribute__((ext_vector_type(8))) short short8;
typedef __attribute__((ext_vector_type(4))) float f32x4;

static __device__ __forceinline__ unsigned short f2bf(float f) {
  unsigned u = __float_as_uint(f);
  u = u + 0x7fffu + ((u >> 16) & 1u);   // RNE
  return (unsigned short)(u >> 16);
}
static __device__ __forceinline__ float bf2f_lo(unsigned v) {
  return __uint_as_float(v << 16);
}
static __device__ __forceinline__ float bf2f_hi(unsigned v) {
  return __uint_as_float(v & 0xffff0000u);
}
static __device__ __forceinline__ unsigned pack_bf2(float a, float b) {
  return (unsigned)f2bf(a) | ((unsigned)f2bf(b) << 16);
}

// ---------------- preprocessing: two-level radix sort by dst ----------------

// pass A: per-bucket histogram (bucket = dst >> 7)
__global__ __launch_bounds__(256) void hist_bucket_kernel(const int* __restrict__ dst,
                                                          int* __restrict__ bcnt,
                                                          int e, int n, int nbk) {
  __shared__ int h[1024];
  int T = e + n;
  int chunk = (T + gridDim.x - 1) / gridDim.x;
  int j0 = blockIdx.x * chunk;
  int j1 = min(j0 + chunk, T);
  for (int i = threadIdx.x; i < nbk; i += 256) h[i] = 0;
  __syncthreads();
  for (int j = j0 + threadIdx.x; j < j1; j += 256) {
    int d = (j < e) ? dst[j] : (j - e);
    atomicAdd(&h[d >> 7], 1);
  }
  __syncthreads();
  for (int i = threadIdx.x; i < nbk; i += 256)
    if (h[i]) atomicAdd(&bcnt[i], h[i]);
}

// pass B prep: exclusive scan of bucket counts (single block)
__global__ __launch_bounds__(1024) void scan_buckets_kernel(const int* __restrict__ bcnt,
                                                            int* __restrict__ bbase,
                                                            int nbk, int total) {
  __shared__ int lds[1024];
  int t = threadIdx.x;
  int v = (t < nbk) ? bcnt[t] : 0;
  int val = v;
  lds[t] = val; __syncthreads();
  for (int off = 1; off < 1024; off <<= 1) {
    int x = (t >= off) ? lds[t - off] : 0;
    __syncthreads();
    val += x;
    lds[t] = val;
    __syncthreads();
  }
  if (t < nbk) bbase[t] = val - v;
  if (t == 0) bbase[nbk] = total;
}

// pass B: scatter edges into bucket regions (contiguous per (block,bucket))
__global__ __launch_bounds__(256) void scatter_bucket_kernel(const int* __restrict__ src,
                                                             const int* __restrict__ dst,
                                                             int* __restrict__ bfill,
                                                             int2* __restrict__ ebuf,
                                                             int e, int n, int nbk) {
  __shared__ int cntL[1024], baseL[1024];
  int T = e + n;
  int chunk = (T + gridDim.x - 1) / gridDim.x;
  int j0 = blockIdx.x * chunk;
  int j1 = min(j0 + chunk, T);
  for (int i = threadIdx.x; i < nbk; i += 256) cntL[i] = 0;
  __syncthreads();
  for (int j = j0 + threadIdx.x; j < j1; j += 256) {
    int d = (j < e) ? dst[j] : (j - e);
    atomicAdd(&cntL[d >> 7], 1);
  }
  __syncthreads();
  for (int i = threadIdx.x; i < nbk; i += 256) {
    int c = cntL[i];
    baseL[i] = c ? atomicAdd(&bfill[i], c) : 0;
    cntL[i] = 0;
  }
  __syncthreads();
  for (int j = j0 + threadIdx.x; j < j1; j += 256) {
    int s, d;
    if (j < e) { s = src[j]; d = dst[j]; } else { s = j - e; d = s; }
    int b = d >> 7;
    int r = atomicAdd(&cntL[b], 1);
    ebuf[baseL[b] + r] = make_int2(s, d);
  }
}

// pass C: in-LDS sort of each bucket by dst; emits rs, dis, sorted src<<6
__global__ __launch_bounds__(256) void sort_bucket_kernel(const int* __restrict__ bbase,
                                                          const int2* __restrict__ ebuf,
                                                          unsigned* __restrict__ esrcw,
                                                          int* __restrict__ rs,
                                                          float* __restrict__ dis,
                                                          int n, int total) {
  __shared__ int2 el[CAP];
  __shared__ int hist[BKT], excl[BKT], cur[BKT], scn[BKT];
  int b = blockIdx.x, t = threadIdx.x;
  int e0 = bbase[b], e1 = bbase[b + 1];
  int sz = e1 - e0;
  bool inl = (sz <= CAP);
  if (inl)
    for (int i = t; i < sz; i += 256) el[i] = ebuf[e0 + i];
  if (t < BKT) hist[t] = 0;
  __syncthreads();
  for (int i = t; i < sz; i += 256) {
    int d = inl ? el[i].y : ebuf[e0 + i].y;
    atomicAdd(&hist[d & (BKT - 1)], 1);
  }
  __syncthreads();
  int val = (t < BKT) ? hist[t] : 0;
  if (t < BKT) scn[t] = val;
  __syncthreads();
  for (int off = 1; off < BKT; off <<= 1) {
    int x = (t >= off && t < BKT) ? scn[t - off] : 0;
    __syncthreads();
    if (t < BKT) { val += x; scn[t] = val; }
    __syncthreads();
  }
  if (t < BKT) {
    int ex = val - hist[t];
    excl[t] = ex;
    cur[t] = 0;
    int d = (b << 7) + t;
    if (d < n) {
      rs[d] = e0 + ex;
      dis[d] = rsqrtf((float)hist[t]);  // deg >= 1 (self-loop)
    }
  }
  if (b == 0 && t == 0) rs[n] = total;
  __syncthreads();
  for (int i = t; i < sz; i += 256) {
    int2 p = inl ? el[i] : ebuf[e0 + i];
    int dl = p.y & (BKT - 1);
    int pos = atomicAdd(&cur[dl], 1);
    esrcw[e0 + excl[dl] + pos] = ((unsigned)p.x) << 6;
  }
}

// per-wave row bounds: A[w] = first row r with rs[r] >= w*EB
__global__ void wave_bounds_kernel(const int* __restrict__ rs, int* __restrict__ A,
                                   int n, int nw, int eb) {
  int w = blockIdx.x * blockDim.x + threadIdx.x;
  if (w > nw) return;
  int target = w * eb;
  int lo = 0, hi = n;
  while (lo < hi) {
    int mid = (lo + hi) >> 1;
    if (rs[mid] < target) lo = mid + 1; else hi = mid;
  }
  A[w] = lo;
}

__global__ void softmax_w_kernel(const float* __restrict__ lw, float* __restrict__ w, int l) {
  if (threadIdx.x == 0 && blockIdx.x == 0) {
    float m = lw[0];
    for (int i = 1; i < l; ++i) m = fmaxf(m, lw[i]);
    float s = 0.f;
    for (int i = 0; i < l; ++i) s += expf(lw[i] - m);
    for (int i = 0; i < l; ++i) w[i] = expf(lw[i] - m) / s;
  }
}

// transpose conv_W to Wt[l][n][k] bf16
__global__ void transpose_w_kernel(const float* __restrict__ W, unsigned short* __restrict__ Wt,
                                   int total) {
  int t = blockIdx.x * blockDim.x + threadIdx.x;
  if (t >= total) return;
  int l = t >> 14;
  int nc = (t >> 7) & 127;
  int kk = t & 127;
  Wt[t] = f2bf(W[(size_t)l * 16384 + kk * 128 + nc]);
}

// ---------------- embed ----------------

__global__ void embed_kernel(const float* __restrict__ x, const float* __restrict__ W,
                             const float* __restrict__ b, float* __restrict__ xe,
                             unsigned short* __restrict__ xebf, int n) {
  int r = blockIdx.x * 2 + (threadIdx.x >> 7);
  int c = threadIdx.x & 127;
  if (r >= n) return;
  float acc = b[c];
#pragma unroll
  for (int k = 0; k < 16; ++k)
    acc = fmaf(x[(size_t)r * 16 + k], W[k * 128 + c], acc);
  xe[(size_t)r * 128 + c] = acc;
  xebf[(size_t)r * 128 + c] = f2bf(acc);
}

// ---------------- fused (BN+ReLU+residual of prev layer) + MFMA GEMM ----------------
// Epilogue scales row r of H by dis[r] (the dis[src] factor of the edge norm).

template<bool HASBN>
__global__ __launch_bounds__(256) void gemm_fused_kernel(
    const unsigned short* __restrict__ Abf,   // !HASBN: bf16 input
    const unsigned* __restrict__ aggbf,       // HASBN: packed bf16x2 agg (prev layer)
    const float* __restrict__ stats8,         // HASBN: 8 slices x 256 (prev layer)
    const float* __restrict__ gamma, const float* __restrict__ beta,
    const float* __restrict__ wsm, int layer, // prev layer idx
    float* __restrict__ xe,
    const unsigned short* __restrict__ Wt,
    const float* __restrict__ dis,
    unsigned short* __restrict__ Hbf, int n) {
  __shared__ short8 wlds[2048];               // 32 KB
  __shared__ float sc_s[128], sh_s[128];
  int tid = threadIdx.x;
  const short* WtS = (const short*)Wt;
#pragma unroll
  for (int it = 0; it < 8; ++it) {
    int s = it * 256 + tid;
    int ln = s & 63, g = s >> 6;              // g = n0*4+ks
    int col = ((g >> 2) << 4) + (ln & 15);
    wlds[s] = *(const short8*)(WtS + (size_t)col * 128 + (g & 3) * 32 + (ln >> 4) * 8);
  }
  if (HASBN && tid < 128) {
    float s = 0.f, q = 0.f;
#pragma unroll
    for (int k = 0; k < 8; ++k) {
      s += stats8[k * 256 + tid];
      q += stats8[k * 256 + 128 + tid];
    }
    float invn = 1.f / (float)n;
    float mean = s * invn;
    float var = q * invn - mean * mean;
    float sc = gamma[tid] * rsqrtf(var + 1e-5f);
    sc_s[tid] = sc;
    sh_s[tid] = beta[tid] - mean * sc;
  }
  __syncthreads();

  int wid = tid >> 6, lane = tid & 63;
  int lrow = lane & 15, lk = lane >> 4;
  float wres = HASBN ? wsm[layer] : 0.f;

  int ntiles = (n + 63) >> 6;
  for (int tile = blockIdx.x; tile < ntiles; tile += gridDim.x) {
    int row = tile * 64 + wid * 16 + lrow;
    short8 afrag[4];
    if (row < n) {
      if (HASBN) {
        const unsigned* arow = aggbf + (size_t)row * 64;
        float* xrow = xe + (size_t)row * 128;
#pragma unroll
        for (int ks = 0; ks < 4; ++ks) {
          int c0 = ks * 32 + lk * 8;
          uint4 av = *(const uint4*)(arow + (c0 >> 1));
          float4 xa = *(const float4*)(xrow + c0);
          float4 xb = *(const float4*)(xrow + c0 + 4);
          unsigned aw[4] = {av.x, av.y, av.z, av.w};
          float xv[8] = {xa.x, xa.y, xa.z, xa.w, xb.x, xb.y, xb.z, xb.w};
          float xn[8];
          short8 af;
#pragma unroll
          for (int d = 0; d < 4; ++d) {
            int c = c0 + 2 * d;
            float v0 = fmaxf(fmaf(bf2f_lo(aw[d]), sc_s[c], sh_s[c]), 0.f);
            float v1 = fmaxf(fmaf(bf2f_hi(aw[d]), sc_s[c + 1], sh_s[c + 1]), 0.f);
            xn[2 * d]     = fmaf(wres, v0, xv[2 * d]);
            xn[2 * d + 1] = fmaf(wres, v1, xv[2 * d + 1]);
          }
          *(float4*)(xrow + c0)     = make_float4(xn[0], xn[1], xn[2], xn[3]);
          *(float4*)(xrow + c0 + 4) = make_float4(xn[4], xn[5], xn[6], xn[7]);
#pragma unroll
          for (int d2 = 0; d2 < 8; ++d2) af[d2] = (short)f2bf(xn[d2]);
          afrag[ks] = af;
        }
      } else {
        const short* AS = (const short*)Abf;
#pragma unroll
        for (int ks = 0; ks < 4; ++ks)
          afrag[ks] = *(const short8*)(AS + (size_t)row * 128 + ks * 32 + lk * 8);
      }
    } else {
#pragma unroll
      for (int ks = 0; ks < 4; ++ks) afrag[ks] = (short8)0;
    }
    f32x4 acc[8];
#pragma unroll
    for (int n0 = 0; n0 < 8; ++n0) acc[n0] = (f32x4)0.f;
#pragma unroll
    for (int ks = 0; ks < 4; ++ks)
#pragma unroll
      for (int n0 = 0; n0 < 8; ++n0)
        acc[n0] = __builtin_amdgcn_mfma_f32_16x16x32_bf16(
            afrag[ks], wlds[(n0 * 4 + ks) * 64 + lane], acc[n0], 0, 0, 0);
    int orow0 = tile * 64 + wid * 16 + lk * 4;
    // dis[src] factor: scale output row r by dis[r] (pad region discarded)
    float4 dv = *(const float4*)(dis + orow0);
    float dsc[4] = {dv.x, dv.y, dv.z, dv.w};
#pragma unroll
    for (int n0 = 0; n0 < 8; ++n0) {
      int col = n0 * 16 + lrow;
#pragma unroll
      for (int r = 0; r < 4; ++r) {
        int orow = orow0 + r;
        if (orow < n) Hbf[(size_t)orow * 128 + col] = f2bf(acc[n0][r] * dsc[r]);
      }
    }
  }
}

// ---------------- flat segmented SpMM + fused BN stats ----------------
// Scalarized bookkeeping (readfirstlane), saddr gathers, 16-deep pipeline.
// agg[d] = dis[d] * sum(h'[src]); h' already carries dis[src].

#define SPMM_STEP(VI, EOFF)                                                \
  {                                                                        \
    a0 += bf2f_lo(VI);                                                     \
    a1 += bf2f_hi(VI);                                                     \
    if (e + (EOFF) + 1 == next) {                                          \
      float x0 = a0 * dr, x1 = a1 * dr;                                    \
      aggbf[(size_t)row * 64 + lane] = pack_bf2(x0, x1);                   \
      s0 += x0; s1 += x1;                                                  \
      q0 = fmaf(x0, x0, q0); q1 = fmaf(x1, x1, q1);                        \
      a0 = 0.f; a1 = 0.f;                                                  \
      ++row;                                                               \
      next = (row < row_end) ? rs[row + 1] : 0x7fffffff;                   \
      dr = (row < row_end) ? dis[row] : 0.f;                               \
    }                                                                      \
  }

__global__ __launch_bounds__(256) void spmm_kernel(
    const int* __restrict__ rs, const int* __restrict__ A,
    const unsigned* __restrict__ esrcw, const unsigned* __restrict__ hb,
    const float* __restrict__ dis,
    unsigned* __restrict__ aggbf, float* __restrict__ stats8, int n) {
  int tid = threadIdx.x;
  int wid = __builtin_amdgcn_readfirstlane(tid >> 6);
  int lane = tid & 63;
  int w = blockIdx.x * 4 + wid;
  int row = __builtin_amdgcn_readfirstlane(A[w]);
  int row_end = __builtin_amdgcn_readfirstlane(A[w + 1]);
  float s0 = 0.f, s1 = 0.f, q0 = 0.f, q1 = 0.f;
  if (row < row_end) {
    int e = __builtin_amdgcn_readfirstlane(rs[row]);
    int eend = __builtin_amdgcn_readfirstlane(rs[row_end]);
    int next = __builtin_amdgcn_readfirstlane(rs[row + 1]);
    float dr = dis[row];
    float a0 = 0.f, a1 = 0.f;
    while (e + 16 <= eend) {
      unsigned sw[16], vv[16];
#pragma unroll
      for (int k = 0; k < 16; ++k) sw[k] = esrcw[e + k];
#pragma unroll
      for (int k = 0; k < 16; ++k) vv[k] = hb[sw[k] + lane];
#pragma unroll
      for (int k = 0; k < 16; ++k) { SPMM_STEP(vv[k], k) }
      e += 16;
    }
    while (e < eend) {
      unsigned v = hb[esrcw[e] + lane];
      SPMM_STEP(v, 0)
      ++e;
    }
  }
  __shared__ float red[4][256];
  red[0][tid] = s0; red[1][tid] = s1; red[2][tid] = q0; red[3][tid] = q1;
  __syncthreads();
  float v = red[wid][lane] + red[wid][64 + lane] + red[wid][128 + lane] + red[wid][192 + lane];
  int c = (wid == 0) ? (2 * lane) : (wid == 1) ? (2 * lane + 1)
        : (wid == 2) ? (128 + 2 * lane) : (129 + 2 * lane);
  atomicAdd(&stats8[(blockIdx.x & 7) * 256 + c], v);
}

// ---------------- final FC (fused BN of last layer) ----------------

__global__ __launch_bounds__(256) void fc_node_kernel(
    const unsigned* __restrict__ aggbf, const float* __restrict__ stats8,
    const float* __restrict__ gamma, const float* __restrict__ beta,
    const float* __restrict__ wsm, int layer,
    const float* __restrict__ xe, const float* __restrict__ fcW,
    float* __restrict__ y, int n) {
  __shared__ float sc_s[128], sh_s[128];
  int tid = threadIdx.x;
  if (tid < 128) {
    float s = 0.f, q = 0.f;
#pragma unroll
    for (int k = 0; k < 8; ++k) {
      s += stats8[k * 256 + tid];
      q += stats8[k * 256 + 128 + tid];
    }
    float invn = 1.f / (float)n;
    float mean = s * invn;
    float var = q * invn - mean * mean;
    float sc = gamma[tid] * rsqrtf(var + 1e-5f);
    sc_s[tid] = sc;
    sh_s[tid] = beta[tid] - mean * sc;
  }
  __syncthreads();
  int wid = tid >> 6, lane = tid & 63;
  int r = blockIdx.x * 4 + wid;
  if (r >= n) return;
  float w = wsm[layer];
  unsigned av = aggbf[(size_t)r * 64 + lane];
  float2 xv = *(const float2*)(xe + (size_t)r * 128 + lane * 2);
  int c0 = lane * 2, c1 = c0 + 1;
  float x0 = fmaf(w, fmaxf(fmaf(bf2f_lo(av), sc_s[c0], sh_s[c0]), 0.f), xv.x);
  float x1 = fmaf(w, fmaxf(fmaf(bf2f_hi(av), sc_s[c1], sh_s[c1]), 0.f), xv.y);
  float a00 = x0 * fcW[c0 * 2 + 0] + x1 * fcW[c1 * 2 + 0];
  float a01 = x0 * fcW[c0 * 2 + 1] + x1 * fcW[c1 * 2 + 1];
  float a10 = x0 * fcW[(128 + c0) * 2 + 0] + x1 * fcW[(128 + c1) * 2 + 0];
  float a11 = x0 * fcW[(128 + c0) * 2 + 1] + x1 * fcW[(128 + c1) * 2 + 1];
#pragma unroll
  for (int off = 32; off; off >>= 1) {
    a00 += __shfl_down(a00, off);
    a01 += __shfl_down(a01, off);
    a10 += __shfl_down(a10, off);
    a11 += __shfl_down(a11, off);
  }
  if (lane == 0) *(float4*)(y + (size_t)r * 4) = make_float4(a00, a01, a10, a11);
}

__global__ void edge_out_kernel(const float* __restrict__ y, const int* __restrict__ eo,
                                const float* __restrict__ fcb, float* __restrict__ out, int m) {
  int j = blockIdx.x * blockDim.x + threadIdx.x;
  if (j >= m) return;
  int a = eo[j], b = eo[m + j];
  float4 ya = *(const float4*)(y + (size_t)a * 4);
  float4 yb = *(const float4*)(y + (size_t)b * 4);
  out[(size_t)j * 2 + 0] = ya.x + yb.z + fcb[0];
  out[(size_t)j * 2 + 1] = ya.y + yb.w + fcb[1];
}

// ---------------------------------------------------------------------------

extern "C" void kernel_launch(void* const* d_in, const int* in_sizes, int n_in,
                              void* d_out, int out_size, void* d_ws, size_t ws_size,
                              hipStream_t stream) {
  const float* x     = (const float*)d_in[0];
  const int*   ei    = (const int*)d_in[1];
  const int*   eo    = (const int*)d_in[2];
  const float* embW  = (const float*)d_in[3];
  const float* embB  = (const float*)d_in[4];
  const float* convW = (const float*)d_in[5];
  const float* gamma = (const float*)d_in[7];
  const float* beta  = (const float*)d_in[8];
  const float* lw    = (const float*)d_in[9];
  const float* fcW   = (const float*)d_in[10];
  const float* fcb   = (const float*)d_in[11];
  float* out = (float*)d_out;

  const int n = in_sizes[0] / 16;          // 100000
  const int e = in_sizes[1] / 2;           // 1600000
  const int m = in_sizes[2] / 2;           // 400000
  const int L = in_sizes[5] / (128 * 128); // 6

  const int T   = e + n;                   // total edges incl self loops
  const int EB  = (T + NW - 1) / NW;       // edges per wave target
  const int nbk = (n + BKT - 1) / BKT;     // 782 buckets

  const int* esrc = ei;
  const int* edst = ei + e;

  char* wsp = (char*)d_ws;
  size_t off = 0;
  auto take = [&](size_t bytes) -> void* {
    void* p = wsp + off;
    off = (off + bytes + 255) & ~(size_t)255;
    return p;
  };
  int*            bcnt     = (int*)take((size_t)(nbk + 1) * 4);
  int*            bbase    = (int*)take((size_t)(nbk + 1) * 4);
  int*            bfill    = (int*)take((size_t)(nbk + 1) * 4);
  int*            rs       = (int*)take((size_t)(n + 1) * 4);
  float*          dis      = (float*)take((size_t)(n + 64) * 4);  // padded for vec reads
  float*          wsm      = (float*)take(64 * 4);
  float*          stats    = (float*)take((size_t)L * 8 * 256 * 4);
  int*            A        = (int*)take((size_t)(NW + 1) * 4);
  int2*           ebuf     = (int2*)take((size_t)T * 8);   // bucketed (src,dst)
  unsigned*       esrcw    = (unsigned*)take((size_t)T * 4); // sorted src<<6
  float*          xe       = (float*)take((size_t)n * 128 * 4);
  unsigned short* xebf     = (unsigned short*)take((size_t)n * 128 * 2);
  unsigned short* hbf      = (unsigned short*)take((size_t)n * 128 * 2);
  unsigned*       aggbf    = (unsigned*)take((size_t)n * 64 * 4);
  unsigned short* Wt       = (unsigned short*)take((size_t)L * 128 * 128 * 2);
  float*          y        = (float*)take((size_t)n * 4 * 4);
  if (off > ws_size || nbk > 1024) return;

  // --- preprocessing: radix sort by dst ---
  hipMemsetAsync(bcnt, 0, (size_t)(nbk + 1) * 4, stream);
  hipMemsetAsync(stats, 0, (size_t)L * 8 * 256 * 4, stream);
  hist_bucket_kernel<<<256, 256, 0, stream>>>(edst, bcnt, e, n, nbk);
  scan_buckets_kernel<<<1, 1024, 0, stream>>>(bcnt, bbase, nbk, T);
  hipMemcpyAsync(bfill, bbase, (size_t)nbk * 4, hipMemcpyDeviceToDevice, stream);
  scatter_bucket_kernel<<<256, 256, 0, stream>>>(esrc, edst, bfill, ebuf, e, n, nbk);
  sort_bucket_kernel<<<nbk, 256, 0, stream>>>(bbase, ebuf, esrcw, rs, dis, n, T);
  wave_bounds_kernel<<<(NW + 256) / 256, 256, 0, stream>>>(rs, A, n, NW, EB);
  softmax_w_kernel<<<1, 64, 0, stream>>>(lw, wsm, L);
  transpose_w_kernel<<<(L * 16384 + 255) / 256, 256, 0, stream>>>(convW, Wt, L * 16384);

  // --- embed ---
  embed_kernel<<<(n + 1) / 2, 256, 0, stream>>>(x, embW, embB, xe, xebf, n);

  // --- 6 GCN layers (conv_b dropped: cancels under BN) ---
  const int ntiles = (n + 63) >> 6;
  const int gemm_grid = (ntiles + 1) / 2;   // exactly <=2 tiles per block
  for (int i = 0; i < L; ++i) {
    if (i == 0) {
      gemm_fused_kernel<false><<<gemm_grid, 256, 0, stream>>>(
          xebf, nullptr, nullptr, nullptr, nullptr, wsm, 0, xe,
          Wt, dis, hbf, n);
    } else {
      gemm_fused_kernel<true><<<gemm_grid, 256, 0, stream>>>(
          nullptr, aggbf, stats + (size_t)(i - 1) * 2048,
          gamma + (size_t)(i - 1) * 128, beta + (size_t)(i - 1) * 128, wsm, i - 1, xe,
          Wt + (size_t)i * 16384, dis, hbf, n);
    }
    spmm_kernel<<<NW / 4, 256, 0, stream>>>(rs, A, esrcw, (const unsigned*)hbf, dis,
                                            aggbf, stats + (size_t)i * 2048, n);
  }

  // --- final FC (fused BN of layer L-1) ---
  fc_node_kernel<<<(n + 3) / 4, 256, 0, stream>>>(
      aggbf, stats + (size_t)(L - 1) * 2048,
      gamma + (size_t)(L - 1) * 128, beta + (size_t)(L - 1) * 128, wsm, L - 1,
      xe, fcW, y, n);
  edge_out_kernel<<<(m + 255) / 256, 256, 0, stream>>>(y, eo, fcb, out, m);
}

// Round 7
// 801.879 us; speedup vs baseline: 1.1877x; 1.1877x over previous
//
#include <hip/hip_runtime.h>

// ---------------------------------------------------------------------------
// MultiEdgeClassifier: 6-layer GCN + BN + weighted residual + edge-pair FC
// N=100k nodes, HID=128, E=1.6M edges (+N self loops), E_OUT=400k
// Round 6: R4 structure restored (packed-norm edges, 8-deep SpMM);
//          GEMM epilogue rewritten as LDS-pack -> coalesced dwordx4 stores.
// ---------------------------------------------------------------------------

#define NW 8192      // waves for spmm (2048 blocks x 4)
#define BKT 128      // dsts per bucket
#define CAP 6144     // max edges per bucket staged in LDS (mean ~2175)

typedef __attribute__((ext_vector_type(8))) short short8;
typedef __attribute__((ext_vector_type(4))) float f32x4;

static __device__ __forceinline__ unsigned short f2bf(float f) {
  unsigned u = __float_as_uint(f);
  u = u + 0x7fffu + ((u >> 16) & 1u);   // RNE
  return (unsigned short)(u >> 16);
}
static __device__ __forceinline__ float bf2f_lo(unsigned v) {
  return __uint_as_float(v << 16);
}
static __device__ __forceinline__ float bf2f_hi(unsigned v) {
  return __uint_as_float(v & 0xffff0000u);
}
static __device__ __forceinline__ unsigned pack_bf2(float a, float b) {
  return (unsigned)f2bf(a) | ((unsigned)f2bf(b) << 16);
}

// ---------------- preprocessing: two-level radix sort by dst ----------------

__global__ __launch_bounds__(256) void hist_bucket_kernel(const int* __restrict__ dst,
                                                          int* __restrict__ bcnt,
                                                          int e, int n, int nbk) {
  __shared__ int h[1024];
  int T = e + n;
  int chunk = (T + gridDim.x - 1) / gridDim.x;
  int j0 = blockIdx.x * chunk;
  int j1 = min(j0 + chunk, T);
  for (int i = threadIdx.x; i < nbk; i += 256) h[i] = 0;
  __syncthreads();
  for (int j = j0 + threadIdx.x; j < j1; j += 256) {
    int d = (j < e) ? dst[j] : (j - e);
    atomicAdd(&h[d >> 7], 1);
  }
  __syncthreads();
  for (int i = threadIdx.x; i < nbk; i += 256)
    if (h[i]) atomicAdd(&bcnt[i], h[i]);
}

__global__ __launch_bounds__(1024) void scan_buckets_kernel(const int* __restrict__ bcnt,
                                                            int* __restrict__ bbase,
                                                            int nbk, int total) {
  __shared__ int lds[1024];
  int t = threadIdx.x;
  int v = (t < nbk) ? bcnt[t] : 0;
  int val = v;
  lds[t] = val; __syncthreads();
  for (int off = 1; off < 1024; off <<= 1) {
    int x = (t >= off) ? lds[t - off] : 0;
    __syncthreads();
    val += x;
    lds[t] = val;
    __syncthreads();
  }
  if (t < nbk) bbase[t] = val - v;
  if (t == 0) bbase[nbk] = total;
}

__global__ __launch_bounds__(256) void scatter_bucket_kernel(const int* __restrict__ src,
                                                             const int* __restrict__ dst,
                                                             int* __restrict__ bfill,
                                                             int2* __restrict__ ebuf,
                                                             int e, int n, int nbk) {
  __shared__ int cntL[1024], baseL[1024];
  int T = e + n;
  int chunk = (T + gridDim.x - 1) / gridDim.x;
  int j0 = blockIdx.x * chunk;
  int j1 = min(j0 + chunk, T);
  for (int i = threadIdx.x; i < nbk; i += 256) cntL[i] = 0;
  __syncthreads();
  for (int j = j0 + threadIdx.x; j < j1; j += 256) {
    int d = (j < e) ? dst[j] : (j - e);
    atomicAdd(&cntL[d >> 7], 1);
  }
  __syncthreads();
  for (int i = threadIdx.x; i < nbk; i += 256) {
    int c = cntL[i];
    baseL[i] = c ? atomicAdd(&bfill[i], c) : 0;
    cntL[i] = 0;
  }
  __syncthreads();
  for (int j = j0 + threadIdx.x; j < j1; j += 256) {
    int s, d;
    if (j < e) { s = src[j]; d = dst[j]; } else { s = j - e; d = s; }
    int b = d >> 7;
    int r = atomicAdd(&cntL[b], 1);
    ebuf[baseL[b] + r] = make_int2(s, d);
  }
}

// pass C: in-LDS sort of each bucket by dst; emits rs, dis, sorted (src,dst)
__global__ __launch_bounds__(256) void sort_bucket_kernel(const int* __restrict__ bbase,
                                                          const int2* __restrict__ ebuf,
                                                          int2* __restrict__ ebuf2,
                                                          int* __restrict__ rs,
                                                          float* __restrict__ dis,
                                                          int n, int total) {
  __shared__ int2 el[CAP];
  __shared__ int hist[BKT], excl[BKT], cur[BKT], scn[BKT];
  int b = blockIdx.x, t = threadIdx.x;
  int e0 = bbase[b], e1 = bbase[b + 1];
  int sz = e1 - e0;
  bool inl = (sz <= CAP);
  if (inl)
    for (int i = t; i < sz; i += 256) el[i] = ebuf[e0 + i];
  if (t < BKT) hist[t] = 0;
  __syncthreads();
  for (int i = t; i < sz; i += 256) {
    int d = inl ? el[i].y : ebuf[e0 + i].y;
    atomicAdd(&hist[d & (BKT - 1)], 1);
  }
  __syncthreads();
  int val = (t < BKT) ? hist[t] : 0;
  if (t < BKT) scn[t] = val;
  __syncthreads();
  for (int off = 1; off < BKT; off <<= 1) {
    int x = (t >= off && t < BKT) ? scn[t - off] : 0;
    __syncthreads();
    if (t < BKT) { val += x; scn[t] = val; }
    __syncthreads();
  }
  if (t < BKT) {
    int ex = val - hist[t];
    excl[t] = ex;
    cur[t] = 0;
    int d = (b << 7) + t;
    if (d < n) {
      rs[d] = e0 + ex;
      dis[d] = rsqrtf((float)hist[t]);  // deg >= 1 (self-loop)
    }
  }
  if (b == 0 && t == 0) rs[n] = total;
  __syncthreads();
  for (int i = t; i < sz; i += 256) {
    int2 p = inl ? el[i] : ebuf[e0 + i];
    int dl = p.y & (BKT - 1);
    int pos = atomicAdd(&cur[dl], 1);
    ebuf2[e0 + excl[dl] + pos] = p;
  }
}

// pass D: (src,dst) -> (src, norm)
__global__ void norm_kernel(const int2* __restrict__ ebuf2, const float* __restrict__ dis,
                            int2* __restrict__ esn, int T) {
  int j = blockIdx.x * blockDim.x + threadIdx.x;
  if (j >= T) return;
  int2 p = ebuf2[j];
  float nm = dis[p.x] * dis[p.y];
  esn[j] = make_int2(p.x, __float_as_int(nm));
}

__global__ void wave_bounds_kernel(const int* __restrict__ rs, int* __restrict__ A,
                                   int n, int nw, int eb) {
  int w = blockIdx.x * blockDim.x + threadIdx.x;
  if (w > nw) return;
  int target = w * eb;
  int lo = 0, hi = n;
  while (lo < hi) {
    int mid = (lo + hi) >> 1;
    if (rs[mid] < target) lo = mid + 1; else hi = mid;
  }
  A[w] = lo;
}

__global__ void softmax_w_kernel(const float* __restrict__ lw, float* __restrict__ w, int l) {
  if (threadIdx.x == 0 && blockIdx.x == 0) {
    float m = lw[0];
    for (int i = 1; i < l; ++i) m = fmaxf(m, lw[i]);
    float s = 0.f;
    for (int i = 0; i < l; ++i) s += expf(lw[i] - m);
    for (int i = 0; i < l; ++i) w[i] = expf(lw[i] - m) / s;
  }
}

__global__ void transpose_w_kernel(const float* __restrict__ W, unsigned short* __restrict__ Wt,
                                   int total) {
  int t = blockIdx.x * blockDim.x + threadIdx.x;
  if (t >= total) return;
  int l = t >> 14;
  int nc = (t >> 7) & 127;
  int kk = t & 127;
  Wt[t] = f2bf(W[(size_t)l * 16384 + kk * 128 + nc]);
}

// ---------------- embed ----------------

__global__ void embed_kernel(const float* __restrict__ x, const float* __restrict__ W,
                             const float* __restrict__ b, float* __restrict__ xe,
                             unsigned short* __restrict__ xebf, int n) {
  int r = blockIdx.x * 2 + (threadIdx.x >> 7);
  int c = threadIdx.x & 127;
  if (r >= n) return;
  float acc = b[c];
#pragma unroll
  for (int k = 0; k < 16; ++k)
    acc = fmaf(x[(size_t)r * 16 + k], W[k * 128 + c], acc);
  xe[(size_t)r * 128 + c] = acc;
  xebf[(size_t)r * 128 + c] = f2bf(acc);
}

// ---------------- fused (BN+ReLU+residual of prev layer) + MFMA GEMM ----------------
// Epilogue: bf16 results packed via padded LDS tile, stored as coalesced dwordx4.

#define EPS 132   // padded LDS row stride (bf16 elems)

template<bool HASBN>
__global__ __launch_bounds__(256) void gemm_fused_kernel(
    const unsigned short* __restrict__ Abf,   // !HASBN: bf16 input
    const unsigned* __restrict__ aggbf,       // HASBN: packed bf16x2 agg (prev layer)
    const float* __restrict__ stats8,         // HASBN: 8 slices x 256 (prev layer)
    const float* __restrict__ gamma, const float* __restrict__ beta,
    const float* __restrict__ wsm, int layer, // prev layer idx
    float* __restrict__ xe,
    const unsigned short* __restrict__ Wt,
    unsigned short* __restrict__ Hbf, int n) {
  __shared__ short8 wlds[2048];               // 32 KB
  __shared__ unsigned short ep[64 * EPS];     // 16.5 KB epilogue pack buffer
  __shared__ float sc_s[128], sh_s[128];
  int tid = threadIdx.x;
  const short* WtS = (const short*)Wt;
#pragma unroll
  for (int it = 0; it < 8; ++it) {
    int s = it * 256 + tid;
    int ln = s & 63, g = s >> 6;              // g = n0*4+ks
    int col = ((g >> 2) << 4) + (ln & 15);
    wlds[s] = *(const short8*)(WtS + (size_t)col * 128 + (g & 3) * 32 + (ln >> 4) * 8);
  }
  if (HASBN && tid < 128) {
    float s = 0.f, q = 0.f;
#pragma unroll
    for (int k = 0; k < 8; ++k) {
      s += stats8[k * 256 + tid];
      q += stats8[k * 256 + 128 + tid];
    }
    float invn = 1.f / (float)n;
    float mean = s * invn;
    float var = q * invn - mean * mean;
    float sc = gamma[tid] * rsqrtf(var + 1e-5f);
    sc_s[tid] = sc;
    sh_s[tid] = beta[tid] - mean * sc;
  }
  __syncthreads();

  int wid = tid >> 6, lane = tid & 63;
  int lrow = lane & 15, lk = lane >> 4;
  float wres = HASBN ? wsm[layer] : 0.f;

  int ntiles = (n + 63) >> 6;
  for (int tile = blockIdx.x; tile < ntiles; tile += gridDim.x) {
    int row = tile * 64 + wid * 16 + lrow;
    short8 afrag[4];
    if (row < n) {
      if (HASBN) {
        const unsigned* arow = aggbf + (size_t)row * 64;
        float* xrow = xe + (size_t)row * 128;
#pragma unroll
        for (int ks = 0; ks < 4; ++ks) {
          int c0 = ks * 32 + lk * 8;
          uint4 av = *(const uint4*)(arow + (c0 >> 1));
          float4 xa = *(const float4*)(xrow + c0);
          float4 xb = *(const float4*)(xrow + c0 + 4);
          unsigned aw[4] = {av.x, av.y, av.z, av.w};
          float xv[8] = {xa.x, xa.y, xa.z, xa.w, xb.x, xb.y, xb.z, xb.w};
          float xn[8];
          short8 af;
#pragma unroll
          for (int d = 0; d < 4; ++d) {
            int c = c0 + 2 * d;
            float v0 = fmaxf(fmaf(bf2f_lo(aw[d]), sc_s[c], sh_s[c]), 0.f);
            float v1 = fmaxf(fmaf(bf2f_hi(aw[d]), sc_s[c + 1], sh_s[c + 1]), 0.f);
            xn[2 * d]     = fmaf(wres, v0, xv[2 * d]);
            xn[2 * d + 1] = fmaf(wres, v1, xv[2 * d + 1]);
          }
          *(float4*)(xrow + c0)     = make_float4(xn[0], xn[1], xn[2], xn[3]);
          *(float4*)(xrow + c0 + 4) = make_float4(xn[4], xn[5], xn[6], xn[7]);
#pragma unroll
          for (int d2 = 0; d2 < 8; ++d2) af[d2] = (short)f2bf(xn[d2]);
          afrag[ks] = af;
        }
      } else {
        const short* AS = (const short*)Abf;
#pragma unroll
        for (int ks = 0; ks < 4; ++ks)
          afrag[ks] = *(const short8*)(AS + (size_t)row * 128 + ks * 32 + lk * 8);
      }
    } else {
#pragma unroll
      for (int ks = 0; ks < 4; ++ks) afrag[ks] = (short8)0;
    }
    f32x4 acc[8];
#pragma unroll
    for (int n0 = 0; n0 < 8; ++n0) acc[n0] = (f32x4)0.f;
#pragma unroll
    for (int ks = 0; ks < 4; ++ks)
#pragma unroll
      for (int n0 = 0; n0 < 8; ++n0)
        acc[n0] = __builtin_amdgcn_mfma_f32_16x16x32_bf16(
            afrag[ks], wlds[(n0 * 4 + ks) * 64 + lane], acc[n0], 0, 0, 0);

    // ---- epilogue: pack to LDS (padded, conflict-free), store coalesced ----
    int eprow0 = wid * 16 + lk * 4;           // row within 64-row tile
#pragma unroll
    for (int n0 = 0; n0 < 8; ++n0) {
      int col = n0 * 16 + lrow;
#pragma unroll
      for (int r = 0; r < 4; ++r)
        ep[(eprow0 + r) * EPS + col] = f2bf(acc[n0][r]);
    }
    __syncthreads();
    int trow = tid >> 2;                      // 0..63
    int tchunk = tid & 3;                     // 4 chunks x 16B... (x4 iters)
    int orow = tile * 64 + trow;
    if (orow < n) {
      unsigned short* dst = Hbf + (size_t)orow * 128;
      const unsigned short* srcl = ep + trow * EPS;
#pragma unroll
      for (int c = 0; c < 4; ++c) {
        int cc = tchunk * 4 + c;              // 16 chunks of 8 bf16
        *(short8*)(dst + cc * 8) = *(const short8*)(srcl + cc * 8);
      }
    }
    __syncthreads();
  }
}

// ---------------- flat segmented SpMM + fused BN stats (R4 form) ----------------

#define SPMM_STEP(PI, VI, EOFF)                                            \
  {                                                                        \
    float nm = __int_as_float(PI.y);                                       \
    a0 = fmaf(nm, bf2f_lo(VI), a0);                                        \
    a1 = fmaf(nm, bf2f_hi(VI), a1);                                        \
    if (e + (EOFF) + 1 == next) {                                          \
      aggbf[(size_t)row * 64 + lane] = pack_bf2(a0, a1);                   \
      s0 += a0; s1 += a1;                                                  \
      q0 = fmaf(a0, a0, q0); q1 = fmaf(a1, a1, q1);                        \
      a0 = 0.f; a1 = 0.f;                                                  \
      ++row;                                                               \
      next = (row < row_end) ? rs[row + 1] : 0x7fffffff;                   \
    }                                                                      \
  }

__global__ __launch_bounds__(256) void spmm_kernel(
    const int* __restrict__ rs, const int* __restrict__ A,
    const int2* __restrict__ esn, const unsigned* __restrict__ hb,
    unsigned* __restrict__ aggbf, float* __restrict__ stats8, int n) {
  int tid = threadIdx.x;
  int wid = tid >> 6, lane = tid & 63;
  int w = blockIdx.x * 4 + wid;
  int row = A[w], row_end = A[w + 1];
  float s0 = 0.f, s1 = 0.f, q0 = 0.f, q1 = 0.f;
  if (row < row_end) {
    int e = rs[row];
    int eend = rs[row_end];
    int next = rs[row + 1];
    float a0 = 0.f, a1 = 0.f;
    while (e + 8 <= eend) {
      int2 p0 = esn[e],     p1 = esn[e + 1], p2 = esn[e + 2], p3 = esn[e + 3];
      int2 p4 = esn[e + 4], p5 = esn[e + 5], p6 = esn[e + 6], p7 = esn[e + 7];
      unsigned v0 = hb[(size_t)p0.x * 64 + lane];
      unsigned v1 = hb[(size_t)p1.x * 64 + lane];
      unsigned v2 = hb[(size_t)p2.x * 64 + lane];
      unsigned v3 = hb[(size_t)p3.x * 64 + lane];
      unsigned v4 = hb[(size_t)p4.x * 64 + lane];
      unsigned v5 = hb[(size_t)p5.x * 64 + lane];
      unsigned v6 = hb[(size_t)p6.x * 64 + lane];
      unsigned v7 = hb[(size_t)p7.x * 64 + lane];
      SPMM_STEP(p0, v0, 0) SPMM_STEP(p1, v1, 1) SPMM_STEP(p2, v2, 2) SPMM_STEP(p3, v3, 3)
      SPMM_STEP(p4, v4, 4) SPMM_STEP(p5, v5, 5) SPMM_STEP(p6, v6, 6) SPMM_STEP(p7, v7, 7)
      e += 8;
    }
    while (e < eend) {
      int2 p = esn[e];
      unsigned v = hb[(size_t)p.x * 64 + lane];
      SPMM_STEP(p, v, 0)
      ++e;
    }
  }
  __shared__ float red[4][256];
  red[0][tid] = s0; red[1][tid] = s1; red[2][tid] = q0; red[3][tid] = q1;
  __syncthreads();
  float v = red[wid][lane] + red[wid][64 + lane] + red[wid][128 + lane] + red[wid][192 + lane];
  int c = (wid == 0) ? (2 * lane) : (wid == 1) ? (2 * lane + 1)
        : (wid == 2) ? (128 + 2 * lane) : (129 + 2 * lane);
  atomicAdd(&stats8[(blockIdx.x & 7) * 256 + c], v);
}

// ---------------- final FC (fused BN of last layer) ----------------

__global__ __launch_bounds__(256) void fc_node_kernel(
    const unsigned* __restrict__ aggbf, const float* __restrict__ stats8,
    const float* __restrict__ gamma, const float* __restrict__ beta,
    const float* __restrict__ wsm, int layer,
    const float* __restrict__ xe, const float* __restrict__ fcW,
    float* __restrict__ y, int n) {
  __shared__ float sc_s[128], sh_s[128];
  int tid = threadIdx.x;
  if (tid < 128) {
    float s = 0.f, q = 0.f;
#pragma unroll
    for (int k = 0; k < 8; ++k) {
      s += stats8[k * 256 + tid];
      q += stats8[k * 256 + 128 + tid];
    }
    float invn = 1.f / (float)n;
    float mean = s * invn;
    float var = q * invn - mean * mean;
    float sc = gamma[tid] * rsqrtf(var + 1e-5f);
    sc_s[tid] = sc;
    sh_s[tid] = beta[tid] - mean * sc;
  }
  __syncthreads();
  int wid = tid >> 6, lane = tid & 63;
  int r = blockIdx.x * 4 + wid;
  if (r >= n) return;
  float w = wsm[layer];
  unsigned av = aggbf[(size_t)r * 64 + lane];
  float2 xv = *(const float2*)(xe + (size_t)r * 128 + lane * 2);
  int c0 = lane * 2, c1 = c0 + 1;
  float x0 = fmaf(w, fmaxf(fmaf(bf2f_lo(av), sc_s[c0], sh_s[c0]), 0.f), xv.x);
  float x1 = fmaf(w, fmaxf(fmaf(bf2f_hi(av), sc_s[c1], sh_s[c1]), 0.f), xv.y);
  float a00 = x0 * fcW[c0 * 2 + 0] + x1 * fcW[c1 * 2 + 0];
  float a01 = x0 * fcW[c0 * 2 + 1] + x1 * fcW[c1 * 2 + 1];
  float a10 = x0 * fcW[(128 + c0) * 2 + 0] + x1 * fcW[(128 + c1) * 2 + 0];
  float a11 = x0 * fcW[(128 + c0) * 2 + 1] + x1 * fcW[(128 + c1) * 2 + 1];
#pragma unroll
  for (int off = 32; off; off >>= 1) {
    a00 += __shfl_down(a00, off);
    a01 += __shfl_down(a01, off);
    a10 += __shfl_down(a10, off);
    a11 += __shfl_down(a11, off);
  }
  if (lane == 0) *(float4*)(y + (size_t)r * 4) = make_float4(a00, a01, a10, a11);
}

__global__ void edge_out_kernel(const float* __restrict__ y, const int* __restrict__ eo,
                                const float* __restrict__ fcb, float* __restrict__ out, int m) {
  int j = blockIdx.x * blockDim.x + threadIdx.x;
  if (j >= m) return;
  int a = eo[j], b = eo[m + j];
  float4 ya = *(const float4*)(y + (size_t)a * 4);
  float4 yb = *(const float4*)(y + (size_t)b * 4);
  out[(size_t)j * 2 + 0] = ya.x + yb.z + fcb[0];
  out[(size_t)j * 2 + 1] = ya.y + yb.w + fcb[1];
}

// ---------------------------------------------------------------------------

extern "C" void kernel_launch(void* const* d_in, const int* in_sizes, int n_in,
                              void* d_out, int out_size, void* d_ws, size_t ws_size,
                              hipStream_t stream) {
  const float* x     = (const float*)d_in[0];
  const int*   ei    = (const int*)d_in[1];
  const int*   eo    = (const int*)d_in[2];
  const float* embW  = (const float*)d_in[3];
  const float* embB  = (const float*)d_in[4];
  const float* convW = (const float*)d_in[5];
  const float* gamma = (const float*)d_in[7];
  const float* beta  = (const float*)d_in[8];
  const float* lw    = (const float*)d_in[9];
  const float* fcW   = (const float*)d_in[10];
  const float* fcb   = (const float*)d_in[11];
  float* out = (float*)d_out;

  const int n = in_sizes[0] / 16;          // 100000
  const int e = in_sizes[1] / 2;           // 1600000
  const int m = in_sizes[2] / 2;           // 400000
  const int L = in_sizes[5] / (128 * 128); // 6

  const int T   = e + n;                   // total edges incl self loops
  const int EB  = (T + NW - 1) / NW;       // edges per wave target
  const int nbk = (n + BKT - 1) / BKT;     // 782 buckets

  const int* esrc = ei;
  const int* edst = ei + e;

  char* wsp = (char*)d_ws;
  size_t off = 0;
  auto take = [&](size_t bytes) -> void* {
    void* p = wsp + off;
    off = (off + bytes + 255) & ~(size_t)255;
    return p;
  };
  int*            bcnt     = (int*)take((size_t)(nbk + 1) * 4);
  int*            bbase    = (int*)take((size_t)(nbk + 1) * 4);
  int*            bfill    = (int*)take((size_t)(nbk + 1) * 4);
  int*            rs       = (int*)take((size_t)(n + 1) * 4);
  float*          dis      = (float*)take((size_t)n * 4);
  float*          wsm      = (float*)take(64 * 4);
  float*          stats    = (float*)take((size_t)L * 8 * 256 * 4);
  int*            A        = (int*)take((size_t)(NW + 1) * 4);
  int2*           ebuf     = (int2*)take((size_t)T * 8);   // bucketed (src,dst); reused as esn
  int2*           ebuf2    = (int2*)take((size_t)T * 8);   // sorted (src,dst)
  float*          xe       = (float*)take((size_t)n * 128 * 4);
  unsigned short* xebf     = (unsigned short*)take((size_t)n * 128 * 2);
  unsigned short* hbf      = (unsigned short*)take((size_t)n * 128 * 2);
  unsigned*       aggbf    = (unsigned*)take((size_t)n * 64 * 4);
  unsigned short* Wt       = (unsigned short*)take((size_t)L * 128 * 128 * 2);
  float*          y        = (float*)take((size_t)n * 4 * 4);
  if (off > ws_size || nbk > 1024) return;

  int2* esn = ebuf;  // alias: pass D reads ebuf2, writes into ebuf's space

  // --- preprocessing: radix sort by dst ---
  hipMemsetAsync(bcnt, 0, (size_t)(nbk + 1) * 4, stream);
  hipMemsetAsync(stats, 0, (size_t)L * 8 * 256 * 4, stream);
  hist_bucket_kernel<<<256, 256, 0, stream>>>(edst, bcnt, e, n, nbk);
  scan_buckets_kernel<<<1, 1024, 0, stream>>>(bcnt, bbase, nbk, T);
  hipMemcpyAsync(bfill, bbase, (size_t)nbk * 4, hipMemcpyDeviceToDevice, stream);
  scatter_bucket_kernel<<<256, 256, 0, stream>>>(esrc, edst, bfill, ebuf, e, n, nbk);
  sort_bucket_kernel<<<nbk, 256, 0, stream>>>(bbase, ebuf, ebuf2, rs, dis, n, T);
  norm_kernel<<<(T + 255) / 256, 256, 0, stream>>>(ebuf2, dis, esn, T);
  wave_bounds_kernel<<<(NW + 256) / 256, 256, 0, stream>>>(rs, A, n, NW, EB);
  softmax_w_kernel<<<1, 64, 0, stream>>>(lw, wsm, L);
  transpose_w_kernel<<<(L * 16384 + 255) / 256, 256, 0, stream>>>(convW, Wt, L * 16384);

  // --- embed ---
  embed_kernel<<<(n + 1) / 2, 256, 0, stream>>>(x, embW, embB, xe, xebf, n);

  // --- 6 GCN layers (conv_b dropped: cancels under BN) ---
  const int ntiles = (n + 63) >> 6;
  const int gemm_grid = (ntiles + 1) / 2;   // exactly <=2 tiles per block
  for (int i = 0; i < L; ++i) {
    if (i == 0) {
      gemm_fused_kernel<false><<<gemm_grid, 256, 0, stream>>>(
          xebf, nullptr, nullptr, nullptr, nullptr, wsm, 0, xe,
          Wt, hbf, n);
    } else {
      gemm_fused_kernel<true><<<gemm_grid, 256, 0, stream>>>(
          nullptr, aggbf, stats + (size_t)(i - 1) * 2048,
          gamma + (size_t)(i - 1) * 128, beta + (size_t)(i - 1) * 128, wsm, i - 1, xe,
          Wt + (size_t)i * 16384, hbf, n);
    }
    spmm_kernel<<<NW / 4, 256, 0, stream>>>(rs, A, esn, (const unsigned*)hbf,
                                            aggbf, stats + (size_t)i * 2048, n);
  }

  // --- final FC (fused BN of layer L-1) ---
  fc_node_kernel<<<(n + 3) / 4, 256, 0, stream>>>(
      aggbf, stats + (size_t)(L - 1) * 2048,
      gamma + (size_t)(L - 1) * 128, beta + (size_t)(L - 1) * 128, wsm, L - 1,
      xe, fcW, y, n);
  edge_out_kernel<<<(m + 255) / 256, 256, 0, stream>>>(y, eo, fcb, out, m);
}

// Round 8
// 797.790 us; speedup vs baseline: 1.1937x; 1.0051x over previous
//
#include <hip/hip_runtime.h>

// ---------------------------------------------------------------------------
// MultiEdgeClassifier: 6-layer GCN + BN + weighted residual + edge-pair FC
// N=100k nodes, HID=128, E=1.6M edges (+N self loops), E_OUT=400k
// Round 7: flag-in-stream SpMM — edge record = (src<<6, norm|endflag);
//          no rs loads / segment compares in the inner loop; int4 pair loads.
// ---------------------------------------------------------------------------

#define NW 8192      // waves for spmm (2048 blocks x 4)
#define BKT 128      // dsts per bucket
#define CAP 6144     // max edges per bucket staged in LDS (mean ~2175)

typedef __attribute__((ext_vector_type(8))) short short8;
typedef __attribute__((ext_vector_type(4))) float f32x4;

static __device__ __forceinline__ unsigned short f2bf(float f) {
  unsigned u = __float_as_uint(f);
  u = u + 0x7fffu + ((u >> 16) & 1u);   // RNE
  return (unsigned short)(u >> 16);
}
static __device__ __forceinline__ float bf2f_lo(unsigned v) {
  return __uint_as_float(v << 16);
}
static __device__ __forceinline__ float bf2f_hi(unsigned v) {
  return __uint_as_float(v & 0xffff0000u);
}
static __device__ __forceinline__ unsigned pack_bf2(float a, float b) {
  return (unsigned)f2bf(a) | ((unsigned)f2bf(b) << 16);
}

// ---------------- preprocessing: two-level radix sort by dst ----------------

__global__ __launch_bounds__(256) void hist_bucket_kernel(const int* __restrict__ dst,
                                                          int* __restrict__ bcnt,
                                                          int e, int n, int nbk) {
  __shared__ int h[1024];
  int T = e + n;
  int chunk = (T + gridDim.x - 1) / gridDim.x;
  int j0 = blockIdx.x * chunk;
  int j1 = min(j0 + chunk, T);
  for (int i = threadIdx.x; i < nbk; i += 256) h[i] = 0;
  __syncthreads();
  for (int j = j0 + threadIdx.x; j < j1; j += 256) {
    int d = (j < e) ? dst[j] : (j - e);
    atomicAdd(&h[d >> 7], 1);
  }
  __syncthreads();
  for (int i = threadIdx.x; i < nbk; i += 256)
    if (h[i]) atomicAdd(&bcnt[i], h[i]);
}

__global__ __launch_bounds__(1024) void scan_buckets_kernel(const int* __restrict__ bcnt,
                                                            int* __restrict__ bbase,
                                                            int nbk, int total) {
  __shared__ int lds[1024];
  int t = threadIdx.x;
  int v = (t < nbk) ? bcnt[t] : 0;
  int val = v;
  lds[t] = val; __syncthreads();
  for (int off = 1; off < 1024; off <<= 1) {
    int x = (t >= off) ? lds[t - off] : 0;
    __syncthreads();
    val += x;
    lds[t] = val;
    __syncthreads();
  }
  if (t < nbk) bbase[t] = val - v;
  if (t == 0) bbase[nbk] = total;
}

__global__ __launch_bounds__(256) void scatter_bucket_kernel(const int* __restrict__ src,
                                                             const int* __restrict__ dst,
                                                             int* __restrict__ bfill,
                                                             int2* __restrict__ ebuf,
                                                             int e, int n, int nbk) {
  __shared__ int cntL[1024], baseL[1024];
  int T = e + n;
  int chunk = (T + gridDim.x - 1) / gridDim.x;
  int j0 = blockIdx.x * chunk;
  int j1 = min(j0 + chunk, T);
  for (int i = threadIdx.x; i < nbk; i += 256) cntL[i] = 0;
  __syncthreads();
  for (int j = j0 + threadIdx.x; j < j1; j += 256) {
    int d = (j < e) ? dst[j] : (j - e);
    atomicAdd(&cntL[d >> 7], 1);
  }
  __syncthreads();
  for (int i = threadIdx.x; i < nbk; i += 256) {
    int c = cntL[i];
    baseL[i] = c ? atomicAdd(&bfill[i], c) : 0;
    cntL[i] = 0;
  }
  __syncthreads();
  for (int j = j0 + threadIdx.x; j < j1; j += 256) {
    int s, d;
    if (j < e) { s = src[j]; d = dst[j]; } else { s = j - e; d = s; }
    int b = d >> 7;
    int r = atomicAdd(&cntL[b], 1);
    ebuf[baseL[b] + r] = make_int2(s, d);
  }
}

// pass C: in-LDS sort of each bucket by dst; emits rs, dis, sorted (src,dst)
__global__ __launch_bounds__(256) void sort_bucket_kernel(const int* __restrict__ bbase,
                                                          const int2* __restrict__ ebuf,
                                                          int2* __restrict__ ebuf2,
                                                          int* __restrict__ rs,
                                                          float* __restrict__ dis,
                                                          int n, int total) {
  __shared__ int2 el[CAP];
  __shared__ int hist[BKT], excl[BKT], cur[BKT], scn[BKT];
  int b = blockIdx.x, t = threadIdx.x;
  int e0 = bbase[b], e1 = bbase[b + 1];
  int sz = e1 - e0;
  bool inl = (sz <= CAP);
  if (inl)
    for (int i = t; i < sz; i += 256) el[i] = ebuf[e0 + i];
  if (t < BKT) hist[t] = 0;
  __syncthreads();
  for (int i = t; i < sz; i += 256) {
    int d = inl ? el[i].y : ebuf[e0 + i].y;
    atomicAdd(&hist[d & (BKT - 1)], 1);
  }
  __syncthreads();
  int val = (t < BKT) ? hist[t] : 0;
  if (t < BKT) scn[t] = val;
  __syncthreads();
  for (int off = 1; off < BKT; off <<= 1) {
    int x = (t >= off && t < BKT) ? scn[t - off] : 0;
    __syncthreads();
    if (t < BKT) { val += x; scn[t] = val; }
    __syncthreads();
  }
  if (t < BKT) {
    int ex = val - hist[t];
    excl[t] = ex;
    cur[t] = 0;
    int d = (b << 7) + t;
    if (d < n) {
      rs[d] = e0 + ex;
      dis[d] = rsqrtf((float)hist[t]);  // deg >= 1 (self-loop)
    }
  }
  if (b == 0 && t == 0) rs[n] = total;
  __syncthreads();
  for (int i = t; i < sz; i += 256) {
    int2 p = inl ? el[i] : ebuf[e0 + i];
    int dl = p.y & (BKT - 1);
    int pos = atomicAdd(&cur[dl], 1);
    ebuf2[e0 + excl[dl] + pos] = p;
  }
}

// pass D: (src,dst) -> (src<<6, norm_bits | end_of_row_flag)
__global__ void norm_kernel(const int2* __restrict__ ebuf2, const float* __restrict__ dis,
                            int2* __restrict__ esn, int T) {
  int j = blockIdx.x * blockDim.x + threadIdx.x;
  if (j >= T) return;
  int2 p = ebuf2[j];
  float nm = dis[p.x] * dis[p.y];
  unsigned bits = __float_as_uint(nm) & 0xfffffffeu;
  // end-of-row: last edge overall, or next edge has different dst
  if (j + 1 == T || ebuf2[j + 1].y != p.y) bits |= 1u;
  esn[j] = make_int2(p.x << 6, (int)bits);
}

__global__ void wave_bounds_kernel(const int* __restrict__ rs, int* __restrict__ A,
                                   int n, int nw, int eb) {
  int w = blockIdx.x * blockDim.x + threadIdx.x;
  if (w > nw) return;
  int target = w * eb;
  int lo = 0, hi = n;
  while (lo < hi) {
    int mid = (lo + hi) >> 1;
    if (rs[mid] < target) lo = mid + 1; else hi = mid;
  }
  A[w] = lo;
}

__global__ void softmax_w_kernel(const float* __restrict__ lw, float* __restrict__ w, int l) {
  if (threadIdx.x == 0 && blockIdx.x == 0) {
    float m = lw[0];
    for (int i = 1; i < l; ++i) m = fmaxf(m, lw[i]);
    float s = 0.f;
    for (int i = 0; i < l; ++i) s += expf(lw[i] - m);
    for (int i = 0; i < l; ++i) w[i] = expf(lw[i] - m) / s;
  }
}

__global__ void transpose_w_kernel(const float* __restrict__ W, unsigned short* __restrict__ Wt,
                                   int total) {
  int t = blockIdx.x * blockDim.x + threadIdx.x;
  if (t >= total) return;
  int l = t >> 14;
  int nc = (t >> 7) & 127;
  int kk = t & 127;
  Wt[t] = f2bf(W[(size_t)l * 16384 + kk * 128 + nc]);
}

// ---------------- embed ----------------

__global__ void embed_kernel(const float* __restrict__ x, const float* __restrict__ W,
                             const float* __restrict__ b, float* __restrict__ xe,
                             unsigned short* __restrict__ xebf, int n) {
  int r = blockIdx.x * 2 + (threadIdx.x >> 7);
  int c = threadIdx.x & 127;
  if (r >= n) return;
  float acc = b[c];
#pragma unroll
  for (int k = 0; k < 16; ++k)
    acc = fmaf(x[(size_t)r * 16 + k], W[k * 128 + c], acc);
  xe[(size_t)r * 128 + c] = acc;
  xebf[(size_t)r * 128 + c] = f2bf(acc);
}

// ---------------- fused (BN+ReLU+residual of prev layer) + MFMA GEMM ----------------
// Epilogue: bf16 results packed via padded LDS tile, stored as coalesced dwordx4.

#define EPS 132   // padded LDS row stride (bf16 elems)

template<bool HASBN>
__global__ __launch_bounds__(256) void gemm_fused_kernel(
    const unsigned short* __restrict__ Abf,   // !HASBN: bf16 input
    const unsigned* __restrict__ aggbf,       // HASBN: packed bf16x2 agg (prev layer)
    const float* __restrict__ stats8,         // HASBN: 8 slices x 256 (prev layer)
    const float* __restrict__ gamma, const float* __restrict__ beta,
    const float* __restrict__ wsm, int layer, // prev layer idx
    float* __restrict__ xe,
    const unsigned short* __restrict__ Wt,
    unsigned short* __restrict__ Hbf, int n) {
  __shared__ short8 wlds[2048];               // 32 KB
  __shared__ unsigned short ep[64 * EPS];     // 16.5 KB epilogue pack buffer
  __shared__ float sc_s[128], sh_s[128];
  int tid = threadIdx.x;
  const short* WtS = (const short*)Wt;
#pragma unroll
  for (int it = 0; it < 8; ++it) {
    int s = it * 256 + tid;
    int ln = s & 63, g = s >> 6;              // g = n0*4+ks
    int col = ((g >> 2) << 4) + (ln & 15);
    wlds[s] = *(const short8*)(WtS + (size_t)col * 128 + (g & 3) * 32 + (ln >> 4) * 8);
  }
  if (HASBN && tid < 128) {
    float s = 0.f, q = 0.f;
#pragma unroll
    for (int k = 0; k < 8; ++k) {
      s += stats8[k * 256 + tid];
      q += stats8[k * 256 + 128 + tid];
    }
    float invn = 1.f / (float)n;
    float mean = s * invn;
    float var = q * invn - mean * mean;
    float sc = gamma[tid] * rsqrtf(var + 1e-5f);
    sc_s[tid] = sc;
    sh_s[tid] = beta[tid] - mean * sc;
  }
  __syncthreads();

  int wid = tid >> 6, lane = tid & 63;
  int lrow = lane & 15, lk = lane >> 4;
  float wres = HASBN ? wsm[layer] : 0.f;

  int ntiles = (n + 63) >> 6;
  for (int tile = blockIdx.x; tile < ntiles; tile += gridDim.x) {
    int row = tile * 64 + wid * 16 + lrow;
    short8 afrag[4];
    if (row < n) {
      if (HASBN) {
        const unsigned* arow = aggbf + (size_t)row * 64;
        float* xrow = xe + (size_t)row * 128;
#pragma unroll
        for (int ks = 0; ks < 4; ++ks) {
          int c0 = ks * 32 + lk * 8;
          uint4 av = *(const uint4*)(arow + (c0 >> 1));
          float4 xa = *(const float4*)(xrow + c0);
          float4 xb = *(const float4*)(xrow + c0 + 4);
          unsigned aw[4] = {av.x, av.y, av.z, av.w};
          float xv[8] = {xa.x, xa.y, xa.z, xa.w, xb.x, xb.y, xb.z, xb.w};
          float xn[8];
          short8 af;
#pragma unroll
          for (int d = 0; d < 4; ++d) {
            int c = c0 + 2 * d;
            float v0 = fmaxf(fmaf(bf2f_lo(aw[d]), sc_s[c], sh_s[c]), 0.f);
            float v1 = fmaxf(fmaf(bf2f_hi(aw[d]), sc_s[c + 1], sh_s[c + 1]), 0.f);
            xn[2 * d]     = fmaf(wres, v0, xv[2 * d]);
            xn[2 * d + 1] = fmaf(wres, v1, xv[2 * d + 1]);
          }
          *(float4*)(xrow + c0)     = make_float4(xn[0], xn[1], xn[2], xn[3]);
          *(float4*)(xrow + c0 + 4) = make_float4(xn[4], xn[5], xn[6], xn[7]);
#pragma unroll
          for (int d2 = 0; d2 < 8; ++d2) af[d2] = (short)f2bf(xn[d2]);
          afrag[ks] = af;
        }
      } else {
        const short* AS = (const short*)Abf;
#pragma unroll
        for (int ks = 0; ks < 4; ++ks)
          afrag[ks] = *(const short8*)(AS + (size_t)row * 128 + ks * 32 + lk * 8);
      }
    } else {
#pragma unroll
      for (int ks = 0; ks < 4; ++ks) afrag[ks] = (short8)0;
    }
    f32x4 acc[8];
#pragma unroll
    for (int n0 = 0; n0 < 8; ++n0) acc[n0] = (f32x4)0.f;
#pragma unroll
    for (int ks = 0; ks < 4; ++ks)
#pragma unroll
      for (int n0 = 0; n0 < 8; ++n0)
        acc[n0] = __builtin_amdgcn_mfma_f32_16x16x32_bf16(
            afrag[ks], wlds[(n0 * 4 + ks) * 64 + lane], acc[n0], 0, 0, 0);

    // ---- epilogue: pack to LDS (padded, conflict-free), store coalesced ----
    int eprow0 = wid * 16 + lk * 4;           // row within 64-row tile
#pragma unroll
    for (int n0 = 0; n0 < 8; ++n0) {
      int col = n0 * 16 + lrow;
#pragma unroll
      for (int r = 0; r < 4; ++r)
        ep[(eprow0 + r) * EPS + col] = f2bf(acc[n0][r]);
    }
    __syncthreads();
    int trow = tid >> 2;                      // 0..63
    int tchunk = tid & 3;
    int orow = tile * 64 + trow;
    if (orow < n) {
      unsigned short* dst = Hbf + (size_t)orow * 128;
      const unsigned short* srcl = ep + trow * EPS;
#pragma unroll
      for (int c = 0; c < 4; ++c) {
        int cc = tchunk * 4 + c;              // 16 chunks of 8 bf16
        *(short8*)(dst + cc * 8) = *(const short8*)(srcl + cc * 8);
      }
    }
    __syncthreads();
  }
}

// ---------------- flag-stream segmented SpMM + fused BN stats ----------------
// Edge record: (src<<6, norm_bits|flag). No rs loads in the loop; flush on flag.

#define SPMM_STEP(SW, NB, VI)                                              \
  {                                                                        \
    float nm = __uint_as_float((unsigned)(NB) & 0xfffffffeu);              \
    a0 = fmaf(nm, bf2f_lo(VI), a0);                                        \
    a1 = fmaf(nm, bf2f_hi(VI), a1);                                        \
    if ((NB) & 1) {                                                        \
      aggbf[(size_t)row * 64 + lane] = pack_bf2(a0, a1);                   \
      t0 += a0; t1 += a1;                                                  \
      u0 = fmaf(a0, a0, u0); u1 = fmaf(a1, a1, u1);                        \
      a0 = 0.f; a1 = 0.f;                                                  \
      ++row;                                                               \
    }                                                                      \
  }

__global__ __launch_bounds__(256) void spmm_kernel(
    const int* __restrict__ rs, const int* __restrict__ A,
    const int2* __restrict__ esn, const unsigned* __restrict__ hb,
    unsigned* __restrict__ aggbf, float* __restrict__ stats8, int n) {
  int tid = threadIdx.x;
  int wid = tid >> 6, lane = tid & 63;
  int w = blockIdx.x * 4 + wid;
  int row = A[w], row_end = A[w + 1];
  float t0 = 0.f, t1 = 0.f, u0 = 0.f, u1 = 0.f;
  if (row < row_end) {
    int e = rs[row];
    int eend = rs[row_end];
    float a0 = 0.f, a1 = 0.f;
    if ((e & 1) && e < eend) {                 // peel to even for int4 pairs
      int2 p = esn[e];
      unsigned v = hb[p.x + lane];
      SPMM_STEP(p.x, p.y, v)
      ++e;
    }
    const int4* esn4 = (const int4*)(esn + e); // 16B-aligned now
    int npair = (eend - e) >> 1;
    int i4 = 0;
    while (i4 + 4 <= npair) {                  // 8 edges per iter
      int4 qa = esn4[i4], qb = esn4[i4 + 1], qc = esn4[i4 + 2], qd = esn4[i4 + 3];
      unsigned v0 = hb[qa.x + lane];
      unsigned v1 = hb[qa.z + lane];
      unsigned v2 = hb[qb.x + lane];
      unsigned v3 = hb[qb.z + lane];
      unsigned v4 = hb[qc.x + lane];
      unsigned v5 = hb[qc.z + lane];
      unsigned v6 = hb[qd.x + lane];
      unsigned v7 = hb[qd.z + lane];
      SPMM_STEP(qa.x, qa.y, v0) SPMM_STEP(qa.z, qa.w, v1)
      SPMM_STEP(qb.x, qb.y, v2) SPMM_STEP(qb.z, qb.w, v3)
      SPMM_STEP(qc.x, qc.y, v4) SPMM_STEP(qc.z, qc.w, v5)
      SPMM_STEP(qd.x, qd.y, v6) SPMM_STEP(qd.z, qd.w, v7)
      i4 += 4;
    }
    e += npair << 3 >> 1;                      // e += i4*2 handled below
    e = e - ((npair & ~3) << 1) + ((npair & ~3) << 1); // no-op guard (clarity)
    e = (int)(((const int2*)esn4 - esn)) + (i4 << 1);
    while (e < eend) {
      int2 p = esn[e];
      unsigned v = hb[p.x + lane];
      SPMM_STEP(p.x, p.y, v)
      ++e;
    }
  }
  __shared__ float red[4][256];
  red[0][tid] = t0; red[1][tid] = t1; red[2][tid] = u0; red[3][tid] = u1;
  __syncthreads();
  float v = red[wid][lane] + red[wid][64 + lane] + red[wid][128 + lane] + red[wid][192 + lane];
  int c = (wid == 0) ? (2 * lane) : (wid == 1) ? (2 * lane + 1)
        : (wid == 2) ? (128 + 2 * lane) : (129 + 2 * lane);
  atomicAdd(&stats8[(blockIdx.x & 7) * 256 + c], v);
}

// ---------------- final FC (fused BN of last layer) ----------------

__global__ __launch_bounds__(256) void fc_node_kernel(
    const unsigned* __restrict__ aggbf, const float* __restrict__ stats8,
    const float* __restrict__ gamma, const float* __restrict__ beta,
    const float* __restrict__ wsm, int layer,
    const float* __restrict__ xe, const float* __restrict__ fcW,
    float* __restrict__ y, int n) {
  __shared__ float sc_s[128], sh_s[128];
  int tid = threadIdx.x;
  if (tid < 128) {
    float s = 0.f, q = 0.f;
#pragma unroll
    for (int k = 0; k < 8; ++k) {
      s += stats8[k * 256 + tid];
      q += stats8[k * 256 + 128 + tid];
    }
    float invn = 1.f / (float)n;
    float mean = s * invn;
    float var = q * invn - mean * mean;
    float sc = gamma[tid] * rsqrtf(var + 1e-5f);
    sc_s[tid] = sc;
    sh_s[tid] = beta[tid] - mean * sc;
  }
  __syncthreads();
  int wid = tid >> 6, lane = tid & 63;
  int r = blockIdx.x * 4 + wid;
  if (r >= n) return;
  float w = wsm[layer];
  unsigned av = aggbf[(size_t)r * 64 + lane];
  float2 xv = *(const float2*)(xe + (size_t)r * 128 + lane * 2);
  int c0 = lane * 2, c1 = c0 + 1;
  float x0 = fmaf(w, fmaxf(fmaf(bf2f_lo(av), sc_s[c0], sh_s[c0]), 0.f), xv.x);
  float x1 = fmaf(w, fmaxf(fmaf(bf2f_hi(av), sc_s[c1], sh_s[c1]), 0.f), xv.y);
  float a00 = x0 * fcW[c0 * 2 + 0] + x1 * fcW[c1 * 2 + 0];
  float a01 = x0 * fcW[c0 * 2 + 1] + x1 * fcW[c1 * 2 + 1];
  float a10 = x0 * fcW[(128 + c0) * 2 + 0] + x1 * fcW[(128 + c1) * 2 + 0];
  float a11 = x0 * fcW[(128 + c0) * 2 + 1] + x1 * fcW[(128 + c1) * 2 + 1];
#pragma unroll
  for (int off = 32; off; off >>= 1) {
    a00 += __shfl_down(a00, off);
    a01 += __shfl_down(a01, off);
    a10 += __shfl_down(a10, off);
    a11 += __shfl_down(a11, off);
  }
  if (lane == 0) *(float4*)(y + (size_t)r * 4) = make_float4(a00, a01, a10, a11);
}

__global__ void edge_out_kernel(const float* __restrict__ y, const int* __restrict__ eo,
                                const float* __restrict__ fcb, float* __restrict__ out, int m) {
  int j = blockIdx.x * blockDim.x + threadIdx.x;
  if (j >= m) return;
  int a = eo[j], b = eo[m + j];
  float4 ya = *(const float4*)(y + (size_t)a * 4);
  float4 yb = *(const float4*)(y + (size_t)b * 4);
  out[(size_t)j * 2 + 0] = ya.x + yb.z + fcb[0];
  out[(size_t)j * 2 + 1] = ya.y + yb.w + fcb[1];
}

// ---------------------------------------------------------------------------

extern "C" void kernel_launch(void* const* d_in, const int* in_sizes, int n_in,
                              void* d_out, int out_size, void* d_ws, size_t ws_size,
                              hipStream_t stream) {
  const float* x     = (const float*)d_in[0];
  const int*   ei    = (const int*)d_in[1];
  const int*   eo    = (const int*)d_in[2];
  const float* embW  = (const float*)d_in[3];
  const float* embB  = (const float*)d_in[4];
  const float* convW = (const float*)d_in[5];
  const float* gamma = (const float*)d_in[7];
  const float* beta  = (const float*)d_in[8];
  const float* lw    = (const float*)d_in[9];
  const float* fcW   = (const float*)d_in[10];
  const float* fcb   = (const float*)d_in[11];
  float* out = (float*)d_out;

  const int n = in_sizes[0] / 16;          // 100000
  const int e = in_sizes[1] / 2;           // 1600000
  const int m = in_sizes[2] / 2;           // 400000
  const int L = in_sizes[5] / (128 * 128); // 6

  const int T   = e + n;                   // total edges incl self loops
  const int EB  = (T + NW - 1) / NW;       // edges per wave target
  const int nbk = (n + BKT - 1) / BKT;     // 782 buckets

  const int* esrc = ei;
  const int* edst = ei + e;

  char* wsp = (char*)d_ws;
  size_t off = 0;
  auto take = [&](size_t bytes) -> void* {
    void* p = wsp + off;
    off = (off + bytes + 255) & ~(size_t)255;
    return p;
  };
  int*            bcnt     = (int*)take((size_t)(nbk + 1) * 4);
  int*            bbase    = (int*)take((size_t)(nbk + 1) * 4);
  int*            bfill    = (int*)take((size_t)(nbk + 1) * 4);
  int*            rs       = (int*)take((size_t)(n + 1) * 4);
  float*          dis      = (float*)take((size_t)n * 4);
  float*          wsm      = (float*)take(64 * 4);
  float*          stats    = (float*)take((size_t)L * 8 * 256 * 4);
  int*            A        = (int*)take((size_t)(NW + 1) * 4);
  int2*           ebuf     = (int2*)take((size_t)T * 8);   // bucketed (src,dst); reused as esn
  int2*           ebuf2    = (int2*)take((size_t)T * 8);   // sorted (src,dst)
  float*          xe       = (float*)take((size_t)n * 128 * 4);
  unsigned short* xebf     = (unsigned short*)take((size_t)n * 128 * 2);
  unsigned short* hbf      = (unsigned short*)take((size_t)n * 128 * 2);
  unsigned*       aggbf    = (unsigned*)take((size_t)n * 64 * 4);
  unsigned short* Wt       = (unsigned short*)take((size_t)L * 128 * 128 * 2);
  float*          y        = (float*)take((size_t)n * 4 * 4);
  if (off > ws_size || nbk > 1024) return;

  int2* esn = ebuf;  // alias: pass D reads ebuf2, writes into ebuf's space

  // --- preprocessing: radix sort by dst ---
  hipMemsetAsync(bcnt, 0, (size_t)(nbk + 1) * 4, stream);
  hipMemsetAsync(stats, 0, (size_t)L * 8 * 256 * 4, stream);
  hist_bucket_kernel<<<256, 256, 0, stream>>>(edst, bcnt, e, n, nbk);
  scan_buckets_kernel<<<1, 1024, 0, stream>>>(bcnt, bbase, nbk, T);
  hipMemcpyAsync(bfill, bbase, (size_t)nbk * 4, hipMemcpyDeviceToDevice, stream);
  scatter_bucket_kernel<<<256, 256, 0, stream>>>(esrc, edst, bfill, ebuf, e, n, nbk);
  sort_bucket_kernel<<<nbk, 256, 0, stream>>>(bbase, ebuf, ebuf2, rs, dis, n, T);
  norm_kernel<<<(T + 255) / 256, 256, 0, stream>>>(ebuf2, dis, esn, T);
  wave_bounds_kernel<<<(NW + 256) / 256, 256, 0, stream>>>(rs, A, n, NW, EB);
  softmax_w_kernel<<<1, 64, 0, stream>>>(lw, wsm, L);
  transpose_w_kernel<<<(L * 16384 + 255) / 256, 256, 0, stream>>>(convW, Wt, L * 16384);

  // --- embed ---
  embed_kernel<<<(n + 1) / 2, 256, 0, stream>>>(x, embW, embB, xe, xebf, n);

  // --- 6 GCN layers (conv_b dropped: cancels under BN) ---
  const int ntiles = (n + 63) >> 6;
  const int gemm_grid = (ntiles + 1) / 2;   // exactly <=2 tiles per block
  for (int i = 0; i < L; ++i) {
    if (i == 0) {
      gemm_fused_kernel<false><<<gemm_grid, 256, 0, stream>>>(
          xebf, nullptr, nullptr, nullptr, nullptr, wsm, 0, xe,
          Wt, hbf, n);
    } else {
      gemm_fused_kernel<true><<<gemm_grid, 256, 0, stream>>>(
          nullptr, aggbf, stats + (size_t)(i - 1) * 2048,
          gamma + (size_t)(i - 1) * 128, beta + (size_t)(i - 1) * 128, wsm, i - 1, xe,
          Wt + (size_t)i * 16384, hbf, n);
    }
    spmm_kernel<<<NW / 4, 256, 0, stream>>>(rs, A, esn, (const unsigned*)hbf,
                                            aggbf, stats + (size_t)i * 2048, n);
  }

  // --- final FC (fused BN of layer L-1) ---
  fc_node_kernel<<<(n + 3) / 4, 256, 0, stream>>>(
      aggbf, stats + (size_t)(L - 1) * 2048,
      gamma + (size_t)(L - 1) * 128, beta + (size_t)(L - 1) * 128, wsm, L - 1,
      xe, fcW, y, n);
  edge_out_kernel<<<(m + 255) / 256, 256, 0, stream>>>(y, eo, fcb, out, m);
}